// Round 8
// baseline (275.182 us; speedup 1.0000x reference)
//
#include <hip/hip_runtime.h>
#include <hip/hip_bf16.h>
#include <math.h>

// SentenceGP: B=16,S=1024,D=1024,M=1024,O=1024
// out = [mean (16,1024,1024) f32][softplus(var) (16,1024,1024) f32]
//
// Pipeline (R8):
//  prep_ipw: ip->bf16 + norms | W->bf16 | rs=0          [one kernel]
//  Kii_reg GEMM (diag=1+noise) + Gershgorin row-sums fused (atomicAdd)
//  gmax: c = 1/max_rowsum, s = sqrt(c)
//  batch1 (z=2): R2 = I-2cK+c^2*K@K | T1 = 2W - c*W@K
//  batch2 (z=2): S  = s(1.5I -c/2*K +11/16*R2 -5c/16*K@R2) -> U[0:1024]
//                W2T= c(T1 + T1@R2)                        -> U[1024:2048]
//  Kxi = exp(-0.5*d2/ls2)  [256^2 GEMM, A = x f32 reg-staged + in-flight
//        bf16 convert + fused row-norms; qb zeroed here; prep_x eliminated]
//  q   = ||Kxi@S||^2 rowwise atomic
//  mean= Kxi@W2T^T + fused var=softplus(1-q) broadcast -> d_out

typedef unsigned short u16;
typedef __attribute__((ext_vector_type(8))) short short8;
typedef __attribute__((ext_vector_type(4))) float f32x4;
typedef __attribute__((ext_vector_type(4))) unsigned short us4;

__device__ __forceinline__ float bf2f(u16 b) {
  union { unsigned u; float f; } x; x.u = ((unsigned)b) << 16; return x.f;
}
__device__ __forceinline__ u16 f2bf(float f) {
  union { float f; unsigned u; } x; x.f = f;
  unsigned r = x.u + 0x7fffu + ((x.u >> 16) & 1u);
  return (u16)(r >> 16);
}

__device__ __forceinline__ void gl_lds16(const void* g, void* l) {
  __builtin_amdgcn_global_load_lds(
      (const __attribute__((address_space(1))) void*)g,
      (__attribute__((address_space(3))) void*)l, 16, 0, 0);
}

// =================== 256^2-tile 8-wave 4-phase/K-tile GEMM ===================
// BM=BN=256, BK=64, 512 threads (8 waves: 2 row x 4 col), NT=16 K-tiles.
// LDS 128 KiB: 2 bufs x (A 32K + B 32K). XOR-swizzled (involution both sides,
// linear dest). Raw s_barrier; counted vmcnt once per K-tile (never 0).
// EPI 0 (CVT): A = x in f32, reg-staged 2 tiles ahead with in-flight bf16
//   convert + ds_write (T14); row sum-of-squares accumulated during convert,
//   exchanged via LDS post-loop. Kxi = bf16(exp(-inv2*max(rn+cn-2c,0))).
//   Also zeroes qb[bid*64..+63] for the later q pass.
// EPI 1: mean f32 store + fused var = softplus(1-q[row]) broadcast
// EPI 2: q[row] += sum_col acc^2  (atomic; Y=Kxi@S never stored)
template <int EPI>
__global__ __launch_bounds__(512, 1) void gemm8(
    const u16* __restrict__ Ag, const float* __restrict__ Axf,
    const u16* __restrict__ Bg,
    float* __restrict__ outF, float* __restrict__ varF,
    u16* __restrict__ outB,
    const float* __restrict__ colN,
    const float* __restrict__ p_ll, float* __restrict__ qb) {
  __shared__ u16 lds[65536];  // 128 KiB
  constexpr int NT = 16;      // K / 64
  constexpr bool CVT = (EPI == 0);
  const int tid = threadIdx.x;
  const int lane = tid & 63;
  const int wave = tid >> 6;
  const int wr = wave >> 2, wc = wave & 3;   // 2 x 4 waves
  const int fro = lane & 15, khi = lane >> 4;
  const int bid = blockIdx.x;                 // 256 blocks
  const int xcd = bid & 7, j5 = bid >> 3;
  const size_t brow = (size_t)(xcd * 8 + (j5 >> 2));  // row-panel -> one XCD
  const size_t bcol = (size_t)(j5 & 3);

  if (CVT) {  // zero q accumulator for the later q dispatch
    if (tid < 64) qb[(size_t)bid * 64 + tid] = 0.0f;
  }

  // staging geometry: thread covers chunks c0=tid, c1=tid+512 of a half-tile
  const int c0 = tid, c1 = tid + 512;
  const int r0 = c0 >> 3, r1 = c1 >> 3;  // r0 in [0,64), r1 = r0+64
  const int gk0 = (c0 & 7) ^ (r0 & 7), gk1 = (c1 & 7) ^ (r1 & 7);
  const int d0 = c0 * 8, d1 = c1 * 8;  // u16 LDS offsets (linear dest)

  f32x4 acc[8][4] = {};
  float4 ra[2][2][2];            // [half][chunk][vec]  (CVT A pipeline regs)
  float np[2][2] = {{0.f, 0.f}, {0.f, 0.f}};  // norm partials [half][chunk]

  auto stageA = [&](int tt, int h, int bb) {
    const u16* s0 = Ag + (size_t)(brow * 256 + h * 128 + r0) * 1024 + tt * 64 + gk0 * 8;
    const u16* s1 = Ag + (size_t)(brow * 256 + h * 128 + r1) * 1024 + tt * 64 + gk1 * 8;
    gl_lds16(s0, &lds[bb * 32768 + h * 8192 + d0]);
    gl_lds16(s1, &lds[bb * 32768 + h * 8192 + d1]);
  };
  auto loadA = [&](int tt) {  // CVT: issue 8 float4 loads (A(tt) -> regs)
#pragma unroll
    for (int h = 0; h < 2; ++h) {
      const float* s0 = Axf + (size_t)(brow * 256 + h * 128 + r0) * 1024 + tt * 64 + gk0 * 8;
      const float* s1 = Axf + (size_t)(brow * 256 + h * 128 + r1) * 1024 + tt * 64 + gk1 * 8;
      ra[h][0][0] = ((const float4*)s0)[0];
      ra[h][0][1] = ((const float4*)s0)[1];
      ra[h][1][0] = ((const float4*)s1)[0];
      ra[h][1][1] = ((const float4*)s1)[1];
    }
  };
  auto writeA = [&](int bb) {  // CVT: convert regs -> bf16, ds_write, norms
#pragma unroll
    for (int h = 0; h < 2; ++h)
#pragma unroll
      for (int ch = 0; ch < 2; ++ch) {
        const float4 v0 = ra[h][ch][0], v1 = ra[h][ch][1];
        np[h][ch] += v0.x * v0.x + v0.y * v0.y + v0.z * v0.z + v0.w * v0.w +
                     v1.x * v1.x + v1.y * v1.y + v1.z * v1.z + v1.w * v1.w;
        short8 o;
        o[0] = (short)f2bf(v0.x); o[1] = (short)f2bf(v0.y);
        o[2] = (short)f2bf(v0.z); o[3] = (short)f2bf(v0.w);
        o[4] = (short)f2bf(v1.x); o[5] = (short)f2bf(v1.y);
        o[6] = (short)f2bf(v1.z); o[7] = (short)f2bf(v1.w);
        *(short8*)&lds[bb * 32768 + h * 8192 + (ch ? d1 : d0)] = o;
      }
  };
  auto stageB = [&](int tt, int h, int bb) {
    const u16* s0 = Bg + (size_t)(bcol * 256 + h * 128 + r0) * 1024 + tt * 64 + gk0 * 8;
    const u16* s1 = Bg + (size_t)(bcol * 256 + h * 128 + r1) * 1024 + tt * 64 + gk1 * 8;
    gl_lds16(s0, &lds[bb * 32768 + 16384 + h * 8192 + d0]);
    gl_lds16(s1, &lds[bb * 32768 + 16384 + h * 8192 + d1]);
  };

  // ---- prologue ----
  if (CVT) {
    loadA(0);
    writeA(0);                     // compiler inserts vmcnt wait for ra
    stageB(0, 0, 0); stageB(0, 1, 0);
    stageB(1, 0, 1); stageB(1, 1, 1);
    loadA(1);
    // outstanding vm: B0(4), B1(4), A1-regs(8) -> retire B0
    asm volatile("s_waitcnt vmcnt(12) lgkmcnt(0)" ::: "memory");
  } else {
    stageA(0, 0, 0); stageA(0, 1, 0);
    stageB(0, 0, 0); stageB(0, 1, 0);
    stageB(1, 0, 1); stageB(1, 1, 1);
    asm volatile("s_waitcnt vmcnt(4)" ::: "memory");
  }
  __builtin_amdgcn_s_barrier();

  for (int t = 0; t < NT; ++t) {
    const int cb = t & 1;
    const int abase = cb * 32768 + wr * 8192;
    const int bbase = cb * 32768 + 16384 + (wc >> 1) * 8192;
    short8 bfrag[4][2];
#pragma unroll
    for (int p = 0; p < 4; ++p) {
      // ---- ds-reads for this phase ----
      short8 afr[2][2];
#pragma unroll
      for (int i = 0; i < 2; ++i) {
        const int rr = (p * 2 + i) * 16 + fro;
#pragma unroll
        for (int s = 0; s < 2; ++s) {
          const int kl = (s * 4 + khi) ^ (rr & 7);
          afr[i][s] = *(const short8*)&lds[abase + (rr * 8 + kl) * 8];
        }
      }
      if (p == 0) {
#pragma unroll
        for (int n = 0; n < 4; ++n) {
          const int cc = (wc & 1) * 64 + n * 16 + fro;
#pragma unroll
          for (int s = 0; s < 2; ++s) {
            const int kl = (s * 4 + khi) ^ (cc & 7);
            bfrag[n][s] = *(const short8*)&lds[bbase + (cc * 8 + kl) * 8];
          }
        }
      }
      // ---- staging ----
      if (p == 0) {
        if (CVT) {
          if (t + 1 < NT) writeA((t + 1) & 1);  // regs loaded last tile
          if (t + 2 < NT) loadA(t + 2);         // issue next loads
        } else {
          if (t + 1 < NT) { stageA(t + 1, 0, (t + 1) & 1); stageA(t + 1, 1, (t + 1) & 1); }
        }
      } else if (p == 1) {
        if (t + 2 < NT) stageB(t + 2, 0, cb);
      } else if (p == 2) {
        if (t + 2 < NT) stageB(t + 2, 1, cb);
      }
      __builtin_amdgcn_s_barrier();
      __builtin_amdgcn_s_setprio(1);
#pragma unroll
      for (int i = 0; i < 2; ++i)
#pragma unroll
        for (int n = 0; n < 4; ++n)
#pragma unroll
          for (int s = 0; s < 2; ++s)
            acc[p * 2 + i][n] = __builtin_amdgcn_mfma_f32_16x16x32_bf16(
                afr[i][s], bfrag[n][s], acc[p * 2 + i][n], 0, 0, 0);
      __builtin_amdgcn_s_setprio(0);
      if (CVT && p == 0)
        asm volatile("s_waitcnt lgkmcnt(0)" ::: "memory");  // drain A ds_writes
      if (p == 3) {
        if (CVT) asm volatile("s_waitcnt vmcnt(12)" ::: "memory");
        else     asm volatile("s_waitcnt vmcnt(4)" ::: "memory");
      }
      __builtin_amdgcn_s_barrier();
    }
  }

  // ---- CVT: exchange row-norm partials through LDS (K-loop LDS is dead) ----
  float* nf = (float*)lds;  // [256][8] partials + [256] row sums at +2048
  if (CVT) {
    __syncthreads();
    nf[(r0) * 8 + (tid & 7)] = np[0][0];
    nf[(r1) * 8 + (tid & 7)] = np[0][1];
    nf[(128 + r0) * 8 + (tid & 7)] = np[1][0];
    nf[(128 + r1) * 8 + (tid & 7)] = np[1][1];
    __syncthreads();
    if (tid < 256) {
      float s = 0.f;
#pragma unroll
      for (int i = 0; i < 8; ++i) s += nf[tid * 8 + i];
      nf[2048 + tid] = s;
    }
    __syncthreads();
  }

  // ---- epilogue ----
  float inv2 = 0.f;
  if (EPI == 0) inv2 = 0.5f * expf(-2.0f * p_ll[0]);
#pragma unroll
  for (int m = 0; m < 8; m++) {
#pragma unroll
    for (int j = 0; j < 4; j++) {
      const int rloc = wr * 128 + m * 16 + khi * 4 + j;
      const size_t grow = brow * 256 + rloc;
      float rn = 0.f, sp = 0.f;
      if (EPI == 0) rn = nf[2048 + rloc];
      if (EPI == 1) {
        float vq = 1.0f - qb[grow];  // K_xx diag == 1 exactly
        sp = fmaxf(vq, 0.f) + log1pf(expf(-fabsf(vq)));
      }
      float part = 0.f;
#pragma unroll
      for (int n = 0; n < 4; n++) {
        const size_t gcol = bcol * 256 + wc * 64 + n * 16 + fro;
        const size_t o = grow * 1024 + gcol;
        float v = acc[m][n][j];
        if (EPI == 0) {
          float d2 = fmaxf(rn + colN[gcol] - 2.0f * v, 0.0f);
          outB[o] = f2bf(expf(-inv2 * d2));
        } else if (EPI == 1) {
          outF[o] = v;
          varF[o] = sp;
        } else {
          part += v * v;
        }
      }
      if (EPI == 2) {
        part += __shfl_xor(part, 1);
        part += __shfl_xor(part, 2);
        part += __shfl_xor(part, 4);
        part += __shfl_xor(part, 8);
        if (fro == 0) atomicAdd(&qb[grow], part);
      }
    }
  }
}

// =================== small 128^2 GEMM core (K=1024, B^T layout) ===========
__device__ __forceinline__ void small_core(const u16* __restrict__ Ap,
                                           const u16* __restrict__ Bp,
                                           u16* As, u16* Bs,
                                           f32x4 (&acc)[4][4]) {
  const int tid = threadIdx.x;
  const int lane = tid & 63;
  const int wave = tid >> 6;
  const int wr = wave >> 1, wc = wave & 1;
  const int idx0 = tid, idx1 = tid + 256;
  const u16* gA0 = Ap + (size_t)(idx0 >> 2) * 1024 + (size_t)(idx0 & 3) * 8;
  const u16* gA1 = Ap + (size_t)(idx1 >> 2) * 1024 + (size_t)(idx1 & 3) * 8;
  const u16* gB0 = Bp + (size_t)(idx0 >> 2) * 1024 + (size_t)(idx0 & 3) * 8;
  const u16* gB1 = Bp + (size_t)(idx1 >> 2) * 1024 + (size_t)(idx1 & 3) * 8;
  u16* lA0 = &As[idx0 * 8]; u16* lA1 = &As[idx1 * 8];
  u16* lB0 = &Bs[idx0 * 8]; u16* lB1 = &Bs[idx1 * 8];
  const int fro = lane & 15;
  const int ko = (lane >> 4) * 8;

  for (int kt = 0; kt < 1024; kt += 32) {
    gl_lds16(gA0 + kt, lA0);
    gl_lds16(gA1 + kt, lA1);
    gl_lds16(gB0 + kt, lB0);
    gl_lds16(gB1 + kt, lB1);
    __syncthreads();
    short8 af[4], bfr[4];
#pragma unroll
    for (int m = 0; m < 4; m++) {
      af[m]  = *(const short8*)&As[(wr * 64 + m * 16 + fro) * 32 + ko];
      bfr[m] = *(const short8*)&Bs[(wc * 64 + m * 16 + fro) * 32 + ko];
    }
#pragma unroll
    for (int m = 0; m < 4; m++)
#pragma unroll
      for (int n = 0; n < 4; n++)
        acc[m][n] = __builtin_amdgcn_mfma_f32_16x16x32_bf16(af[m], bfr[n], acc[m][n], 0, 0, 0);
    __syncthreads();
  }
}

// Kii_reg: rbf(ip,ip), diag = 1+noise; fused Gershgorin row |sum| atomics
__global__ __launch_bounds__(256) void gemm_kii(const u16* __restrict__ ipb,
                                                u16* __restrict__ kii,
                                                const float* __restrict__ ni,
                                                const float* __restrict__ ll,
                                                const float* __restrict__ ln,
                                                float* __restrict__ rs) {
  __shared__ u16 As[4096], Bs[4096];
  f32x4 acc[4][4] = {};
  small_core(ipb + (size_t)blockIdx.y * 131072, ipb + (size_t)blockIdx.x * 131072,
             As, Bs, acc);
  const int lane = threadIdx.x & 63;
  const int wave = threadIdx.x >> 6;
  const int wr = wave >> 1, wc = wave & 1;
  float inv2 = 0.5f * expf(-2.0f * ll[0]);
  float noise = expf(ln[0]);
#pragma unroll
  for (int m = 0; m < 4; m++)
#pragma unroll
    for (int j = 0; j < 4; j++) {
      const size_t grow = blockIdx.y * 128 + wr * 64 + m * 16 + (lane >> 4) * 4 + j;
      float rn = ni[grow];
      float part = 0.f;
#pragma unroll
      for (int n = 0; n < 4; n++) {
        const size_t gcol = blockIdx.x * 128 + wc * 64 + n * 16 + (lane & 15);
        float d2 = fmaxf(rn + ni[gcol] - 2.0f * acc[m][n][j], 0.0f);
        float kv = (grow == gcol) ? (1.0f + noise) : expf(-inv2 * d2);
        kii[grow * 1024 + gcol] = f2bf(kv);
        part += fabsf(kv);
      }
      part += __shfl_xor(part, 1);
      part += __shfl_xor(part, 2);
      part += __shfl_xor(part, 4);
      part += __shfl_xor(part, 8);
      if ((lane & 15) == 0) atomicAdd(&rs[grow], part);
    }
}

// batch1: z=0: R2 = I - 2cK + c^2*(K@K) ; z=1: T1 = 2W - c*(W@K)
__global__ __launch_bounds__(256) void gemm_batch1(const u16* __restrict__ kii,
                                                   const u16* __restrict__ Wb,
                                                   u16* __restrict__ R2b,
                                                   u16* __restrict__ T1b,
                                                   const float* __restrict__ sc) {
  __shared__ u16 As[4096], Bs[4096];
  f32x4 acc[4][4] = {};
  const int z = blockIdx.z;
  const u16* Abase = z ? Wb : kii;
  small_core(Abase + (size_t)blockIdx.y * 131072, kii + (size_t)blockIdx.x * 131072,
             As, Bs, acc);
  const int lane = threadIdx.x & 63;
  const int wave = threadIdx.x >> 6;
  const int wr = wave >> 1, wc = wave & 1;
  const float c = sc[0];
#pragma unroll
  for (int m = 0; m < 4; m++)
#pragma unroll
    for (int j = 0; j < 4; j++) {
      const size_t grow = blockIdx.y * 128 + wr * 64 + m * 16 + (lane >> 4) * 4 + j;
#pragma unroll
      for (int n = 0; n < 4; n++) {
        const size_t gcol = blockIdx.x * 128 + wc * 64 + n * 16 + (lane & 15);
        const size_t o = grow * 1024 + gcol;
        float v = acc[m][n][j];
        if (z == 0) {
          float idv = (grow == gcol) ? 1.0f : 0.0f;
          R2b[o] = f2bf(idv - 2.0f * c * bf2f(kii[o]) + c * c * v);
        } else {
          T1b[o] = f2bf(2.0f * bf2f(Wb[o]) - c * v);
        }
      }
    }
}

// batch2: z=0: U[0:1024]    = S = s*(1.5I - c/2*K + 11/16*R2 - 5c/16*(K@R2))
//         z=1: U[1024:2048] = W2T = c*(T1 + T1@R2)
__global__ __launch_bounds__(256) void gemm_batch2(const u16* __restrict__ kii,
                                                   const u16* __restrict__ R2b,
                                                   const u16* __restrict__ T1b,
                                                   u16* __restrict__ U,
                                                   const float* __restrict__ sc) {
  __shared__ u16 As[4096], Bs[4096];
  f32x4 acc[4][4] = {};
  const int z = blockIdx.z;
  const u16* Abase = z ? T1b : kii;
  small_core(Abase + (size_t)blockIdx.y * 131072, R2b + (size_t)blockIdx.x * 131072,
             As, Bs, acc);
  const int lane = threadIdx.x & 63;
  const int wave = threadIdx.x >> 6;
  const int wr = wave >> 1, wc = wave & 1;
  const float c = sc[0], s = sc[1];
#pragma unroll
  for (int m = 0; m < 4; m++)
#pragma unroll
    for (int j = 0; j < 4; j++) {
      const size_t grow = blockIdx.y * 128 + wr * 64 + m * 16 + (lane >> 4) * 4 + j;
#pragma unroll
      for (int n = 0; n < 4; n++) {
        const size_t gcol = blockIdx.x * 128 + wc * 64 + n * 16 + (lane & 15);
        const size_t o = grow * 1024 + gcol;
        float v = acc[m][n][j];
        if (z == 0) {
          float idv = (grow == gcol) ? 1.0f : 0.0f;
          U[o] = f2bf(s * (1.5f * idv - 0.5f * c * bf2f(kii[o]) +
                           0.6875f * bf2f(R2b[o]) - 0.3125f * c * v));
        } else {
          U[o + 1048576] = f2bf(c * (bf2f(T1b[o]) + v));
        }
      }
    }
}

// ---------- ip rows (norms) + W convert + rs zero, one kernel ----------
__global__ __launch_bounds__(256) void prep_ipw(const float* __restrict__ ip,
                                                const float* __restrict__ W,
                                                u16* __restrict__ ipb,
                                                u16* __restrict__ wbf,
                                                float* __restrict__ ni,
                                                float* __restrict__ rs) {
  __shared__ float wsum[4];
  int b = blockIdx.x;
  if (b < 1024) {
    const float4 v = ((const float4*)(ip + (size_t)b * 1024))[threadIdx.x];
    float ss = v.x * v.x + v.y * v.y + v.z * v.z + v.w * v.w;
    us4 o; o.x = f2bf(v.x); o.y = f2bf(v.y); o.z = f2bf(v.z); o.w = f2bf(v.w);
    ((us4*)(ipb + (size_t)b * 1024))[threadIdx.x] = o;
#pragma unroll
    for (int s = 32; s > 0; s >>= 1) ss += __shfl_xor(ss, s);
    if ((threadIdx.x & 63) == 0) wsum[threadIdx.x >> 6] = ss;
    __syncthreads();
    if (threadIdx.x == 0) {
      ni[b] = wsum[0] + wsum[1] + wsum[2] + wsum[3];
      rs[b] = 0.0f;
    }
  } else {
    int r = b - 1024;
    const float4 v = ((const float4*)(W + (size_t)r * 1024))[threadIdx.x];
    us4 o; o.x = f2bf(v.x); o.y = f2bf(v.y); o.z = f2bf(v.z); o.w = f2bf(v.w);
    ((us4*)(wbf + (size_t)r * 1024))[threadIdx.x] = o;
  }
}

__global__ __launch_bounds__(256) void gmax_inv(const float* __restrict__ rs,
                                                float* __restrict__ sc) {
  __shared__ float wm[4];
  float m = 0.f;
  for (int i = threadIdx.x; i < 1024; i += 256) m = fmaxf(m, rs[i]);
#pragma unroll
  for (int o = 32; o > 0; o >>= 1) m = fmaxf(m, __shfl_xor(m, o));
  if ((threadIdx.x & 63) == 0) wm[threadIdx.x >> 6] = m;
  __syncthreads();
  if (threadIdx.x == 0) {
    float c = 1.0f / fmaxf(fmaxf(wm[0], wm[1]), fmaxf(wm[2], wm[3]));
    sc[0] = c;
    sc[1] = sqrtf(c);
  }
}

extern "C" void kernel_launch(void* const* d_in, const int* in_sizes, int n_in,
                              void* d_out, int out_size, void* d_ws, size_t ws_size,
                              hipStream_t stream) {
  const float* x  = (const float*)d_in[0];
  const float* ip = (const float*)d_in[1];
  const float* ll = (const float*)d_in[2];
  const float* ln = (const float*)d_in[3];
  const float* W  = (const float*)d_in[4];

  char* ws = (char*)d_ws;
  const size_t MB = 1ull << 20;
  u16* kxib = (u16*)(ws + 0 * MB);    // 32 MiB
  u16* ipb  = (u16*)(ws + 64 * MB);   // 2 MiB
  u16* wbf  = (u16*)(ws + 66 * MB);   // 2 MiB
  u16* kii  = (u16*)(ws + 68 * MB);   // 2 MiB
  u16* R2b  = (u16*)(ws + 70 * MB);   // 2 MiB
  u16* Ub   = (u16*)(ws + 74 * MB);   // 4 MiB  [S ; W2T]
  u16* t1b  = (u16*)(ws + 78 * MB);   // 2 MiB
  float* qb = (float*)(ws + 80 * MB + 128 * 1024);
  float* ni = (float*)(ws + 80 * MB + 256 * 1024);
  float* rs = (float*)(ws + 80 * MB + 512 * 1024);
  float* sc = (float*)(ws + 80 * MB + 768 * 1024);

  float* meanO = (float*)d_out;
  float* varO  = meanO + 16777216ull;

  prep_ipw<<<2048, 256, 0, stream>>>(ip, W, ipb, wbf, ni, rs);

  // Kii_reg + fused Gershgorin row-sums
  gemm_kii<<<dim3(8, 8), 256, 0, stream>>>(ipb, kii, ni, ll, ln, rs);
  gmax_inv<<<1, 256, 0, stream>>>(rs, sc);

  // batched: {R2 ; T1} then {S -> U[0:1024] ; W2T -> U[1024:2048]}
  gemm_batch1<<<dim3(8, 8, 2), 256, 0, stream>>>(kii, wbf, R2b, t1b, sc);
  gemm_batch2<<<dim3(8, 8, 2), 256, 0, stream>>>(kii, R2b, t1b, Ub, sc);

  // Kxi = exp(-inv2*d2(x,ip)); x converted in-flight, norms fused, qb zeroed
  gemm8<0><<<256, 512, 0, stream>>>(nullptr, x, ipb, nullptr, nullptr, kxib,
                                    ni, ll, qb);
  // q[s] = ||Kxi@S||^2 rowwise (atomic)
  gemm8<2><<<256, 512, 0, stream>>>(kxib, nullptr, Ub, nullptr, nullptr,
                                    nullptr, nullptr, nullptr, qb);
  // mean = Kxi@W2T^T -> d_out, fused var = softplus(1-q) broadcast
  gemm8<1><<<256, 512, 0, stream>>>(kxib, nullptr, Ub + 1048576, meanO, varO,
                                    nullptr, nullptr, nullptr, qb);
}

// Round 9
// 244.489 us; speedup vs baseline: 1.1255x; 1.1255x over previous
//
#include <hip/hip_runtime.h>
#include <hip/hip_bf16.h>
#include <math.h>

// SentenceGP: B=16,S=1024,D=1024,M=1024,O=1024
// out = [mean (16,1024,1024) f32][softplus(var) (16,1024,1024) f32]
//
// Pipeline (R9 = R7 structure + deeper-staggered gemm8 prefetch):
//  prep_x: x->bf16 + row norms
//  prep_ipw: ip->bf16 + norms | W->bf16 | rs=0
//  Kii_reg GEMM (diag=1+noise) + Gershgorin row-sums fused (atomicAdd)
//  gmax: c = 1/max_rowsum, s = sqrt(c)
//  batch1 (z=2): R2 = I-2cK+c^2*K@K | T1 = 2W - c*W@K
//  batch2 (z=2): S  = s(1.5I -c/2*K +11/16*R2 -5c/16*K@R2) -> U[0:1024]
//                W2T= c(T1 + T1@R2)                        -> U[1024:2048]
//  Kxi = exp(-0.5*d2/ls2)  [256^2 GEMM; qb zeroed here]
//  q   = ||Kxi@S||^2 rowwise atomic
//  mean= Kxi@W2T^T + fused var=softplus(1-q) broadcast -> d_out
//
// R9 gemm8 staging (staggered half-tiles, m201-style counted vmcnt):
//  p0: A(t+1,h1) -> buf^1   p1: B(t+2,h0) -> cb   p2: B(t+2,h1)+A(t+2,h0) -> cb
//  p3: vmcnt(6) steady (3 half-tiles in flight), vmcnt(0) last two tiles.
//  Every half-tile gets ~6 phases (~900+ cy) of HBM-latency cover.

typedef unsigned short u16;
typedef __attribute__((ext_vector_type(8))) short short8;
typedef __attribute__((ext_vector_type(4))) float f32x4;
typedef __attribute__((ext_vector_type(4))) unsigned short us4;

__device__ __forceinline__ float bf2f(u16 b) {
  union { unsigned u; float f; } x; x.u = ((unsigned)b) << 16; return x.f;
}
__device__ __forceinline__ u16 f2bf(float f) {
  union { float f; unsigned u; } x; x.f = f;
  unsigned r = x.u + 0x7fffu + ((x.u >> 16) & 1u);
  return (u16)(r >> 16);
}

__device__ __forceinline__ void gl_lds16(const void* g, void* l) {
  __builtin_amdgcn_global_load_lds(
      (const __attribute__((address_space(1))) void*)g,
      (__attribute__((address_space(3))) void*)l, 16, 0, 0);
}

// =================== 256^2-tile 8-wave 4-phase/K-tile GEMM ===================
// BM=BN=256, BK=64, 512 threads (8 waves: 2 row x 4 col), NT=16 K-tiles.
// LDS 128 KiB: 2 bufs x (A 32K + B 32K). XOR-swizzled (involution both sides,
// linear gl_lds dest). Raw s_barrier only; vmcnt(6) once per K-tile.
// WAR safety: each region staged only after the barrier that closes the phase
// of its last ds_read (A h0: read p0/p1, staged p2; A h1: read p2/p3, staged
// next-tile p0 into other buf; B: read p0, staged p1/p2 two tiles ahead).
// EPI 0: Kxi = bf16(exp(-inv2*max(rn+cn-2c,0))); zeroes qb for the q pass.
// EPI 1: mean f32 store + fused var = softplus(1-q[row]) broadcast
// EPI 2: q[row] += sum_col acc^2  (atomic; Y=Kxi@S never stored)
template <int EPI>
__global__ __launch_bounds__(512, 1) void gemm8(
    const u16* __restrict__ Ag, const u16* __restrict__ Bg,
    float* __restrict__ outF, float* __restrict__ varF,
    u16* __restrict__ outB,
    const float* __restrict__ rowN, const float* __restrict__ colN,
    const float* __restrict__ p_ll, float* __restrict__ qb) {
  __shared__ u16 lds[65536];  // 128 KiB
  constexpr int NT = 16;      // K / 64
  const int tid = threadIdx.x;
  const int lane = tid & 63;
  const int wave = tid >> 6;
  const int wr = wave >> 2, wc = wave & 3;   // 2 x 4 waves
  const int fro = lane & 15, khi = lane >> 4;
  const int bid = blockIdx.x;                 // 256 blocks
  const int xcd = bid & 7, j5 = bid >> 3;
  const size_t brow = (size_t)(xcd * 8 + (j5 >> 2));  // row-panel -> one XCD
  const size_t bcol = (size_t)(j5 & 3);

  if (EPI == 0) {  // zero q accumulator for the later q dispatch
    if (tid < 64) qb[(size_t)bid * 64 + tid] = 0.0f;
  }

  // staging geometry: thread covers chunks c0=tid, c1=tid+512 of a half-tile
  const int c0 = tid, c1 = tid + 512;
  const int r0 = c0 >> 3, r1 = c1 >> 3;
  const int gk0 = (c0 & 7) ^ (r0 & 7), gk1 = (c1 & 7) ^ (r1 & 7);
  const int d0 = c0 * 8, d1 = c1 * 8;  // u16 LDS offsets (linear dest)

  f32x4 acc[8][4] = {};

  auto stageA = [&](int tt, int h, int bb) {
    const u16* s0 = Ag + (size_t)(brow * 256 + h * 128 + r0) * 1024 + tt * 64 + gk0 * 8;
    const u16* s1 = Ag + (size_t)(brow * 256 + h * 128 + r1) * 1024 + tt * 64 + gk1 * 8;
    gl_lds16(s0, &lds[bb * 32768 + h * 8192 + d0]);
    gl_lds16(s1, &lds[bb * 32768 + h * 8192 + d1]);
  };
  auto stageB = [&](int tt, int h, int bb) {
    const u16* s0 = Bg + (size_t)(bcol * 256 + h * 128 + r0) * 1024 + tt * 64 + gk0 * 8;
    const u16* s1 = Bg + (size_t)(bcol * 256 + h * 128 + r1) * 1024 + tt * 64 + gk1 * 8;
    gl_lds16(s0, &lds[bb * 32768 + 16384 + h * 8192 + d0]);
    gl_lds16(s1, &lds[bb * 32768 + 16384 + h * 8192 + d1]);
  };

  // prologue: A(0)+B(0) -> buf0, B(1)+A(1,h0) -> buf1.
  // vmcnt(6): A(0),B(0) landed; B(1)x4 + A(1,h0)x2 stay in flight.
  stageA(0, 0, 0); stageA(0, 1, 0);
  stageB(0, 0, 0); stageB(0, 1, 0);
  stageB(1, 0, 1); stageB(1, 1, 1);
  stageA(1, 0, 1);
  asm volatile("s_waitcnt vmcnt(6)" ::: "memory");
  __builtin_amdgcn_s_barrier();

  for (int t = 0; t < NT; ++t) {
    const int cb = t & 1;
    const int abase = cb * 32768 + wr * 8192;
    const int bbase = cb * 32768 + 16384 + (wc >> 1) * 8192;
    short8 bfrag[4][2];
#pragma unroll
    for (int p = 0; p < 4; ++p) {
      // ---- ds-reads for this phase ----
      short8 afr[2][2];
#pragma unroll
      for (int i = 0; i < 2; ++i) {
        const int rr = (p * 2 + i) * 16 + fro;
#pragma unroll
        for (int s = 0; s < 2; ++s) {
          const int kl = (s * 4 + khi) ^ (rr & 7);
          afr[i][s] = *(const short8*)&lds[abase + (rr * 8 + kl) * 8];
        }
      }
      if (p == 0) {
#pragma unroll
        for (int n = 0; n < 4; ++n) {
          const int cc = (wc & 1) * 64 + n * 16 + fro;
#pragma unroll
          for (int s = 0; s < 2; ++s) {
            const int kl = (s * 4 + khi) ^ (cc & 7);
            bfrag[n][s] = *(const short8*)&lds[bbase + (cc * 8 + kl) * 8];
          }
        }
      }
      // ---- staggered staging ----
      if (p == 0) {
        if (t + 1 < NT) stageA(t + 1, 1, (t + 1) & 1);  // A(t-1) h1 done @ t-1 p3
      } else if (p == 1) {
        if (t + 2 < NT) stageB(t + 2, 0, cb);           // B(t) fully read @ p0
      } else if (p == 2) {
        if (t + 2 < NT) {
          stageB(t + 2, 1, cb);
          stageA(t + 2, 0, cb);                         // A(t) h0 done @ p1
        }
      }
      __builtin_amdgcn_s_barrier();
      __builtin_amdgcn_s_setprio(1);
#pragma unroll
      for (int i = 0; i < 2; ++i)
#pragma unroll
        for (int n = 0; n < 4; ++n)
#pragma unroll
          for (int s = 0; s < 2; ++s)
            acc[p * 2 + i][n] = __builtin_amdgcn_mfma_f32_16x16x32_bf16(
                afr[i][s], bfrag[n][s], acc[p * 2 + i][n], 0, 0, 0);
      __builtin_amdgcn_s_setprio(0);
      if (p == 3) {
        if (t < NT - 2) asm volatile("s_waitcnt vmcnt(6)" ::: "memory");
        else            asm volatile("s_waitcnt vmcnt(0)" ::: "memory");
      }
      __builtin_amdgcn_s_barrier();
    }
  }

  // ---- epilogue ----
  float inv2 = 0.f;
  if (EPI == 0) inv2 = 0.5f * expf(-2.0f * p_ll[0]);
#pragma unroll
  for (int m = 0; m < 8; m++) {
#pragma unroll
    for (int j = 0; j < 4; j++) {
      const size_t grow = brow * 256 + wr * 128 + m * 16 + khi * 4 + j;
      float rn = 0.f, sp = 0.f;
      if (EPI == 0) rn = rowN[grow];
      if (EPI == 1) {
        float vq = 1.0f - qb[grow];  // K_xx diag == 1 exactly
        sp = fmaxf(vq, 0.f) + log1pf(expf(-fabsf(vq)));
      }
      float part = 0.f;
#pragma unroll
      for (int n = 0; n < 4; n++) {
        const size_t gcol = bcol * 256 + wc * 64 + n * 16 + fro;
        const size_t o = grow * 1024 + gcol;
        float v = acc[m][n][j];
        if (EPI == 0) {
          float d2 = fmaxf(rn + colN[gcol] - 2.0f * v, 0.0f);
          outB[o] = f2bf(expf(-inv2 * d2));
        } else if (EPI == 1) {
          outF[o] = v;
          varF[o] = sp;
        } else {
          part += v * v;
        }
      }
      if (EPI == 2) {
        part += __shfl_xor(part, 1);
        part += __shfl_xor(part, 2);
        part += __shfl_xor(part, 4);
        part += __shfl_xor(part, 8);
        if (fro == 0) atomicAdd(&qb[grow], part);
      }
    }
  }
}

// =================== small 128^2 GEMM core (K=1024, B^T layout) ===========
__device__ __forceinline__ void small_core(const u16* __restrict__ Ap,
                                           const u16* __restrict__ Bp,
                                           u16* As, u16* Bs,
                                           f32x4 (&acc)[4][4]) {
  const int tid = threadIdx.x;
  const int lane = tid & 63;
  const int wave = tid >> 6;
  const int wr = wave >> 1, wc = wave & 1;
  const int idx0 = tid, idx1 = tid + 256;
  const u16* gA0 = Ap + (size_t)(idx0 >> 2) * 1024 + (size_t)(idx0 & 3) * 8;
  const u16* gA1 = Ap + (size_t)(idx1 >> 2) * 1024 + (size_t)(idx1 & 3) * 8;
  const u16* gB0 = Bp + (size_t)(idx0 >> 2) * 1024 + (size_t)(idx0 & 3) * 8;
  const u16* gB1 = Bp + (size_t)(idx1 >> 2) * 1024 + (size_t)(idx1 & 3) * 8;
  u16* lA0 = &As[idx0 * 8]; u16* lA1 = &As[idx1 * 8];
  u16* lB0 = &Bs[idx0 * 8]; u16* lB1 = &Bs[idx1 * 8];
  const int fro = lane & 15;
  const int ko = (lane >> 4) * 8;

  for (int kt = 0; kt < 1024; kt += 32) {
    gl_lds16(gA0 + kt, lA0);
    gl_lds16(gA1 + kt, lA1);
    gl_lds16(gB0 + kt, lB0);
    gl_lds16(gB1 + kt, lB1);
    __syncthreads();
    short8 af[4], bfr[4];
#pragma unroll
    for (int m = 0; m < 4; m++) {
      af[m]  = *(const short8*)&As[(wr * 64 + m * 16 + fro) * 32 + ko];
      bfr[m] = *(const short8*)&Bs[(wc * 64 + m * 16 + fro) * 32 + ko];
    }
#pragma unroll
    for (int m = 0; m < 4; m++)
#pragma unroll
      for (int n = 0; n < 4; n++)
        acc[m][n] = __builtin_amdgcn_mfma_f32_16x16x32_bf16(af[m], bfr[n], acc[m][n], 0, 0, 0);
    __syncthreads();
  }
}

// Kii_reg: rbf(ip,ip), diag = 1+noise; fused Gershgorin row |sum| atomics
__global__ __launch_bounds__(256) void gemm_kii(const u16* __restrict__ ipb,
                                                u16* __restrict__ kii,
                                                const float* __restrict__ ni,
                                                const float* __restrict__ ll,
                                                const float* __restrict__ ln,
                                                float* __restrict__ rs) {
  __shared__ u16 As[4096], Bs[4096];
  f32x4 acc[4][4] = {};
  small_core(ipb + (size_t)blockIdx.y * 131072, ipb + (size_t)blockIdx.x * 131072,
             As, Bs, acc);
  const int lane = threadIdx.x & 63;
  const int wave = threadIdx.x >> 6;
  const int wr = wave >> 1, wc = wave & 1;
  float inv2 = 0.5f * expf(-2.0f * ll[0]);
  float noise = expf(ln[0]);
#pragma unroll
  for (int m = 0; m < 4; m++)
#pragma unroll
    for (int j = 0; j < 4; j++) {
      const size_t grow = blockIdx.y * 128 + wr * 64 + m * 16 + (lane >> 4) * 4 + j;
      float rn = ni[grow];
      float part = 0.f;
#pragma unroll
      for (int n = 0; n < 4; n++) {
        const size_t gcol = blockIdx.x * 128 + wc * 64 + n * 16 + (lane & 15);
        float d2 = fmaxf(rn + ni[gcol] - 2.0f * acc[m][n][j], 0.0f);
        float kv = (grow == gcol) ? (1.0f + noise) : expf(-inv2 * d2);
        kii[grow * 1024 + gcol] = f2bf(kv);
        part += fabsf(kv);
      }
      part += __shfl_xor(part, 1);
      part += __shfl_xor(part, 2);
      part += __shfl_xor(part, 4);
      part += __shfl_xor(part, 8);
      if ((lane & 15) == 0) atomicAdd(&rs[grow], part);
    }
}

// batch1: z=0: R2 = I - 2cK + c^2*(K@K) ; z=1: T1 = 2W - c*(W@K)
__global__ __launch_bounds__(256) void gemm_batch1(const u16* __restrict__ kii,
                                                   const u16* __restrict__ Wb,
                                                   u16* __restrict__ R2b,
                                                   u16* __restrict__ T1b,
                                                   const float* __restrict__ sc) {
  __shared__ u16 As[4096], Bs[4096];
  f32x4 acc[4][4] = {};
  const int z = blockIdx.z;
  const u16* Abase = z ? Wb : kii;
  small_core(Abase + (size_t)blockIdx.y * 131072, kii + (size_t)blockIdx.x * 131072,
             As, Bs, acc);
  const int lane = threadIdx.x & 63;
  const int wave = threadIdx.x >> 6;
  const int wr = wave >> 1, wc = wave & 1;
  const float c = sc[0];
#pragma unroll
  for (int m = 0; m < 4; m++)
#pragma unroll
    for (int j = 0; j < 4; j++) {
      const size_t grow = blockIdx.y * 128 + wr * 64 + m * 16 + (lane >> 4) * 4 + j;
#pragma unroll
      for (int n = 0; n < 4; n++) {
        const size_t gcol = blockIdx.x * 128 + wc * 64 + n * 16 + (lane & 15);
        const size_t o = grow * 1024 + gcol;
        float v = acc[m][n][j];
        if (z == 0) {
          float idv = (grow == gcol) ? 1.0f : 0.0f;
          R2b[o] = f2bf(idv - 2.0f * c * bf2f(kii[o]) + c * c * v);
        } else {
          T1b[o] = f2bf(2.0f * bf2f(Wb[o]) - c * v);
        }
      }
    }
}

// batch2: z=0: U[0:1024]    = S = s*(1.5I - c/2*K + 11/16*R2 - 5c/16*(K@R2))
//         z=1: U[1024:2048] = W2T = c*(T1 + T1@R2)
__global__ __launch_bounds__(256) void gemm_batch2(const u16* __restrict__ kii,
                                                   const u16* __restrict__ R2b,
                                                   const u16* __restrict__ T1b,
                                                   u16* __restrict__ U,
                                                   const float* __restrict__ sc) {
  __shared__ u16 As[4096], Bs[4096];
  f32x4 acc[4][4] = {};
  const int z = blockIdx.z;
  const u16* Abase = z ? T1b : kii;
  small_core(Abase + (size_t)blockIdx.y * 131072, R2b + (size_t)blockIdx.x * 131072,
             As, Bs, acc);
  const int lane = threadIdx.x & 63;
  const int wave = threadIdx.x >> 6;
  const int wr = wave >> 1, wc = wave & 1;
  const float c = sc[0], s = sc[1];
#pragma unroll
  for (int m = 0; m < 4; m++)
#pragma unroll
    for (int j = 0; j < 4; j++) {
      const size_t grow = blockIdx.y * 128 + wr * 64 + m * 16 + (lane >> 4) * 4 + j;
#pragma unroll
      for (int n = 0; n < 4; n++) {
        const size_t gcol = blockIdx.x * 128 + wc * 64 + n * 16 + (lane & 15);
        const size_t o = grow * 1024 + gcol;
        float v = acc[m][n][j];
        if (z == 0) {
          float idv = (grow == gcol) ? 1.0f : 0.0f;
          U[o] = f2bf(s * (1.5f * idv - 0.5f * c * bf2f(kii[o]) +
                           0.6875f * bf2f(R2b[o]) - 0.3125f * c * v));
        } else {
          U[o + 1048576] = f2bf(c * (bf2f(T1b[o]) + v));
        }
      }
    }
}

// ---------- prep: f32 rows (R x 1024) -> bf16 + row sum-of-squares ----------
__global__ __launch_bounds__(256) void prep_rows(const float* __restrict__ in,
                                                 u16* __restrict__ outb,
                                                 float* __restrict__ norms, int R) {
  __shared__ float wsum[4];
  for (int r = blockIdx.x; r < R; r += gridDim.x) {
    const float4 v = ((const float4*)(in + (size_t)r * 1024))[threadIdx.x];
    float ss = v.x * v.x + v.y * v.y + v.z * v.z + v.w * v.w;
    us4 o; o.x = f2bf(v.x); o.y = f2bf(v.y); o.z = f2bf(v.z); o.w = f2bf(v.w);
    ((us4*)(outb + (size_t)r * 1024))[threadIdx.x] = o;
#pragma unroll
    for (int s = 32; s > 0; s >>= 1) ss += __shfl_xor(ss, s);
    if ((threadIdx.x & 63) == 0) wsum[threadIdx.x >> 6] = ss;
    __syncthreads();
    if (threadIdx.x == 0) norms[r] = wsum[0] + wsum[1] + wsum[2] + wsum[3];
    __syncthreads();
  }
}

// ---------- ip rows (norms) + W convert + rs zero, one kernel ----------
__global__ __launch_bounds__(256) void prep_ipw(const float* __restrict__ ip,
                                                const float* __restrict__ W,
                                                u16* __restrict__ ipb,
                                                u16* __restrict__ wbf,
                                                float* __restrict__ ni,
                                                float* __restrict__ rs) {
  __shared__ float wsum[4];
  int b = blockIdx.x;
  if (b < 1024) {
    const float4 v = ((const float4*)(ip + (size_t)b * 1024))[threadIdx.x];
    float ss = v.x * v.x + v.y * v.y + v.z * v.z + v.w * v.w;
    us4 o; o.x = f2bf(v.x); o.y = f2bf(v.y); o.z = f2bf(v.z); o.w = f2bf(v.w);
    ((us4*)(ipb + (size_t)b * 1024))[threadIdx.x] = o;
#pragma unroll
    for (int s = 32; s > 0; s >>= 1) ss += __shfl_xor(ss, s);
    if ((threadIdx.x & 63) == 0) wsum[threadIdx.x >> 6] = ss;
    __syncthreads();
    if (threadIdx.x == 0) {
      ni[b] = wsum[0] + wsum[1] + wsum[2] + wsum[3];
      rs[b] = 0.0f;
    }
  } else {
    int r = b - 1024;
    const float4 v = ((const float4*)(W + (size_t)r * 1024))[threadIdx.x];
    us4 o; o.x = f2bf(v.x); o.y = f2bf(v.y); o.z = f2bf(v.z); o.w = f2bf(v.w);
    ((us4*)(wbf + (size_t)r * 1024))[threadIdx.x] = o;
  }
}

__global__ __launch_bounds__(256) void gmax_inv(const float* __restrict__ rs,
                                                float* __restrict__ sc) {
  __shared__ float wm[4];
  float m = 0.f;
  for (int i = threadIdx.x; i < 1024; i += 256) m = fmaxf(m, rs[i]);
#pragma unroll
  for (int o = 32; o > 0; o >>= 1) m = fmaxf(m, __shfl_xor(m, o));
  if ((threadIdx.x & 63) == 0) wm[threadIdx.x >> 6] = m;
  __syncthreads();
  if (threadIdx.x == 0) {
    float c = 1.0f / fmaxf(fmaxf(wm[0], wm[1]), fmaxf(wm[2], wm[3]));
    sc[0] = c;
    sc[1] = sqrtf(c);
  }
}

extern "C" void kernel_launch(void* const* d_in, const int* in_sizes, int n_in,
                              void* d_out, int out_size, void* d_ws, size_t ws_size,
                              hipStream_t stream) {
  const float* x  = (const float*)d_in[0];
  const float* ip = (const float*)d_in[1];
  const float* ll = (const float*)d_in[2];
  const float* ln = (const float*)d_in[3];
  const float* W  = (const float*)d_in[4];

  char* ws = (char*)d_ws;
  const size_t MB = 1ull << 20;
  u16* kxib = (u16*)(ws + 0 * MB);    // 32 MiB
  u16* xbf  = (u16*)(ws + 32 * MB);   // 32 MiB
  u16* ipb  = (u16*)(ws + 64 * MB);   // 2 MiB
  u16* wbf  = (u16*)(ws + 66 * MB);   // 2 MiB
  u16* kii  = (u16*)(ws + 68 * MB);   // 2 MiB
  u16* R2b  = (u16*)(ws + 70 * MB);   // 2 MiB
  u16* Ub   = (u16*)(ws + 74 * MB);   // 4 MiB  [S ; W2T]
  u16* t1b  = (u16*)(ws + 78 * MB);   // 2 MiB
  float* nx = (float*)(ws + 80 * MB);
  float* qb = (float*)(ws + 80 * MB + 128 * 1024);
  float* ni = (float*)(ws + 80 * MB + 256 * 1024);
  float* rs = (float*)(ws + 80 * MB + 512 * 1024);
  float* sc = (float*)(ws + 80 * MB + 768 * 1024);

  float* meanO = (float*)d_out;
  float* varO  = meanO + 16777216ull;

  prep_rows<<<2048, 256, 0, stream>>>(x, xbf, nx, 16384);
  prep_ipw<<<2048, 256, 0, stream>>>(ip, W, ipb, wbf, ni, rs);

  // Kii_reg + fused Gershgorin row-sums
  gemm_kii<<<dim3(8, 8), 256, 0, stream>>>(ipb, kii, ni, ll, ln, rs);
  gmax_inv<<<1, 256, 0, stream>>>(rs, sc);

  // batched: {R2 ; T1} then {S -> U[0:1024] ; W2T -> U[1024:2048]}
  gemm_batch1<<<dim3(8, 8, 2), 256, 0, stream>>>(kii, wbf, R2b, t1b, sc);
  gemm_batch2<<<dim3(8, 8, 2), 256, 0, stream>>>(kii, R2b, t1b, Ub, sc);

  // Kxi = exp(-inv2 * d2(x, ip)); qb zeroed here
  gemm8<0><<<256, 512, 0, stream>>>(xbf, ipb, nullptr, nullptr, kxib,
                                    nx, ni, ll, qb);
  // q[s] = ||Kxi@S||^2 rowwise (atomic)
  gemm8<2><<<256, 512, 0, stream>>>(kxib, Ub, nullptr, nullptr, nullptr,
                                    nullptr, nullptr, nullptr, qb);
  // mean = Kxi@W2T^T -> d_out, fused var = softplus(1-q) broadcast
  gemm8<1><<<256, 512, 0, stream>>>(kxib, Ub + 1048576, meanO, varO, nullptr,
                                    nullptr, nullptr, nullptr, qb);
}

// Round 10
// 239.909 us; speedup vs baseline: 1.1470x; 1.0191x over previous
//
#include <hip/hip_runtime.h>
#include <hip/hip_bf16.h>
#include <math.h>

// SentenceGP: B=16,S=1024,D=1024,M=1024,O=1024
// out = [mean (16,1024,1024) f32][softplus(var) (16,1024,1024) f32]
//
// Pipeline (R10):
//  prep_x: x->bf16 + row norms
//  prep_ipw: ip->bf16 + norms | W->bf16 | rs=0
//  Kii_reg GEMM (diag=1+noise) + Gershgorin row-sums fused
//  gmax: c = 1/max_rowsum, s = sqrt(c)
//  batch1 (z=2): R2 = I-2cK+c^2*K@K | T1 = 2W - c*W@K
//  batch2 (z=2): S -> U[0:1024] | W2T -> U[1024:2048]
//  Kxi = exp(-0.5*d2/ls2)            [gemm128; qb zeroed here]
//  q   = ||Kxi@S||^2 rowwise atomic  [gemm128]
//  mean= Kxi@W2T^T + fused var       [gemm128]
//
// R10 big-GEMM: 128x128 tile, BK=64, 4 waves, 64 KiB LDS -> 2 blocks/CU
// (grid 1024 = 4 generations). Block-level TLP hides barriers, prologue
// fetch and epilogue writes (the 1-block/CU lockstep was the R5-R9 24%
// MfmaUtil ceiling). Counted vmcnt(4)/tile; ONE barrier per phase (WAR
// pairs all separated by phase-end barriers); XOR-swizzled LDS.

typedef unsigned short u16;
typedef __attribute__((ext_vector_type(8))) short short8;
typedef __attribute__((ext_vector_type(4))) float f32x4;
typedef __attribute__((ext_vector_type(4))) unsigned short us4;

__device__ __forceinline__ float bf2f(u16 b) {
  union { unsigned u; float f; } x; x.u = ((unsigned)b) << 16; return x.f;
}
__device__ __forceinline__ u16 f2bf(float f) {
  union { float f; unsigned u; } x; x.f = f;
  unsigned r = x.u + 0x7fffu + ((x.u >> 16) & 1u);
  return (u16)(r >> 16);
}

__device__ __forceinline__ void gl_lds16(const void* g, void* l) {
  __builtin_amdgcn_global_load_lds(
      (const __attribute__((address_space(1))) void*)g,
      (__attribute__((address_space(3))) void*)l, 16, 0, 0);
}

// =================== 128^2-tile 4-wave GEMM, 2 blocks/CU ===================
// BM=BN=128, BK=64, 256 threads (4 waves: 2 row x 2 col), NT=16 K-tiles.
// LDS 64 KiB: 2 bufs x (A 16K + B 16K). XOR-swizzle: LDS chunk (r,kl) holds
// global (r, kl ^ (r&7)); gl_lds dest linear; read applies same involution.
// Staging: p0: A(t+1)->buf^1 (A(t-1) last read @ t-1 p3); p1: B(t+2)->cb
// (B(t) fully read @ p0). vmcnt(4) @ p3 (B(t+2) stays in flight), vmcnt(0)
// last two tiles. One s_barrier per phase (end).
// EPI 0: Kxi = bf16(exp(-inv2*max(rn+cn-2c,0))); zeroes qb.
// EPI 1: mean f32 store + fused var = softplus(1-q[row]).
// EPI 2: q[row] += sum_col acc^2 (atomic).
template <int EPI>
__global__ __launch_bounds__(256, 2) void gemm128(
    const u16* __restrict__ Ag, const u16* __restrict__ Bg,
    float* __restrict__ outF, float* __restrict__ varF,
    u16* __restrict__ outB,
    const float* __restrict__ rowN, const float* __restrict__ colN,
    const float* __restrict__ p_ll, float* __restrict__ qb) {
  __shared__ u16 lds[32768];  // 64 KiB
  constexpr int NT = 16;      // K / 64
  const int tid = threadIdx.x;
  const int lane = tid & 63;
  const int wave = tid >> 6;                  // 4 waves
  const int wr = wave >> 1, wc = wave & 1;    // 2 x 2
  const int fro = lane & 15, khi = lane >> 4;
  const int bid = blockIdx.x;                 // 1024 blocks
  const int xcd = bid & 7, j7 = bid >> 3;
  const size_t brow = (size_t)(xcd * 16 + (j7 >> 3));  // 8 col-blocks/panel on one XCD
  const size_t bcol = (size_t)(j7 & 7);

  if (EPI == 0) {  // zero q accumulator for the later q pass
    if (tid < 16) qb[(size_t)bid * 16 + tid] = 0.0f;
  }

  f32x4 acc[4][4] = {};

  auto stageA = [&](int tt, int bb) {
#pragma unroll
    for (int c = 0; c < 4; ++c) {
      const int ci = tid + 256 * c;      // 1024 chunks of 8 u16
      const int row = ci >> 3;           // 0..127
      const int gk = (ci & 7) ^ (row & 7);
      gl_lds16(Ag + (size_t)(brow * 128 + row) * 1024 + tt * 64 + gk * 8,
               &lds[bb * 16384 + ci * 8]);
    }
  };
  auto stageB = [&](int tt, int bb) {
#pragma unroll
    for (int c = 0; c < 4; ++c) {
      const int ci = tid + 256 * c;
      const int row = ci >> 3;
      const int gk = (ci & 7) ^ (row & 7);
      gl_lds16(Bg + (size_t)(bcol * 128 + row) * 1024 + tt * 64 + gk * 8,
               &lds[bb * 16384 + 8192 + ci * 8]);
    }
  };

  // prologue: A(0)+B(0) -> buf0, B(1) -> buf1. vmcnt(4): tile0 landed.
  stageA(0, 0);
  stageB(0, 0);
  stageB(1, 1);
  asm volatile("s_waitcnt vmcnt(4)" ::: "memory");
  __builtin_amdgcn_s_barrier();

  for (int t = 0; t < NT; ++t) {
    const int cb = t & 1;
    const int ab = cb * 16384;
    const int bb = cb * 16384 + 8192;
    short8 bfrag[4][2];
#pragma unroll
    for (int p = 0; p < 4; ++p) {
      // ---- ds-reads for this phase ----
      short8 afr[2];
      const int rr = wr * 64 + p * 16 + fro;
#pragma unroll
      for (int s = 0; s < 2; ++s) {
        const int kl = (s * 4 + khi) ^ (rr & 7);
        afr[s] = *(const short8*)&lds[ab + (rr * 8 + kl) * 8];
      }
      if (p == 0) {
#pragma unroll
        for (int n = 0; n < 4; ++n) {
          const int cc = wc * 64 + n * 16 + fro;
#pragma unroll
          for (int s = 0; s < 2; ++s) {
            const int kl = (s * 4 + khi) ^ (cc & 7);
            bfrag[n][s] = *(const short8*)&lds[bb + (cc * 8 + kl) * 8];
          }
        }
        if (t + 1 < NT) stageA(t + 1, cb ^ 1);   // A(t-1) done @ t-1 p3
      } else if (p == 1) {
        if (t + 2 < NT) stageB(t + 2, cb);        // B(t) done @ p0
      }
      __builtin_amdgcn_s_setprio(1);
#pragma unroll
      for (int n = 0; n < 4; ++n)
#pragma unroll
        for (int s = 0; s < 2; ++s)
          acc[p][n] = __builtin_amdgcn_mfma_f32_16x16x32_bf16(
              afr[s], bfrag[n][s], acc[p][n], 0, 0, 0);
      __builtin_amdgcn_s_setprio(0);
      if (p == 3) {
        if (t < NT - 2) asm volatile("s_waitcnt vmcnt(4)" ::: "memory");
        else            asm volatile("s_waitcnt vmcnt(0)" ::: "memory");
      }
      __builtin_amdgcn_s_barrier();
    }
  }

  // ---- epilogue ----
  float inv2 = 0.f;
  if (EPI == 0) inv2 = 0.5f * expf(-2.0f * p_ll[0]);
#pragma unroll
  for (int m = 0; m < 4; m++) {
#pragma unroll
    for (int j = 0; j < 4; j++) {
      const size_t grow = brow * 128 + wr * 64 + m * 16 + khi * 4 + j;
      float rn = 0.f, sp = 0.f;
      if (EPI == 0) rn = rowN[grow];
      if (EPI == 1) {
        float vq = 1.0f - qb[grow];  // K_xx diag == 1 exactly
        sp = fmaxf(vq, 0.f) + log1pf(expf(-fabsf(vq)));
      }
      float part = 0.f;
#pragma unroll
      for (int n = 0; n < 4; n++) {
        const size_t gcol = bcol * 128 + wc * 64 + n * 16 + fro;
        const size_t o = grow * 1024 + gcol;
        float v = acc[m][n][j];
        if (EPI == 0) {
          float d2 = fmaxf(rn + colN[gcol] - 2.0f * v, 0.0f);
          outB[o] = f2bf(expf(-inv2 * d2));
        } else if (EPI == 1) {
          outF[o] = v;
          varF[o] = sp;
        } else {
          part += v * v;
        }
      }
      if (EPI == 2) {
        part += __shfl_xor(part, 1);
        part += __shfl_xor(part, 2);
        part += __shfl_xor(part, 4);
        part += __shfl_xor(part, 8);
        if (fro == 0) atomicAdd(&qb[grow], part);
      }
    }
  }
}

// =================== small 128^2 GEMM core (K=1024, B^T layout) ===========
__device__ __forceinline__ void small_core(const u16* __restrict__ Ap,
                                           const u16* __restrict__ Bp,
                                           u16* As, u16* Bs,
                                           f32x4 (&acc)[4][4]) {
  const int tid = threadIdx.x;
  const int lane = tid & 63;
  const int wave = tid >> 6;
  const int wr = wave >> 1, wc = wave & 1;
  const int idx0 = tid, idx1 = tid + 256;
  const u16* gA0 = Ap + (size_t)(idx0 >> 2) * 1024 + (size_t)(idx0 & 3) * 8;
  const u16* gA1 = Ap + (size_t)(idx1 >> 2) * 1024 + (size_t)(idx1 & 3) * 8;
  const u16* gB0 = Bp + (size_t)(idx0 >> 2) * 1024 + (size_t)(idx0 & 3) * 8;
  const u16* gB1 = Bp + (size_t)(idx1 >> 2) * 1024 + (size_t)(idx1 & 3) * 8;
  u16* lA0 = &As[idx0 * 8]; u16* lA1 = &As[idx1 * 8];
  u16* lB0 = &Bs[idx0 * 8]; u16* lB1 = &Bs[idx1 * 8];
  const int fro = lane & 15;
  const int ko = (lane >> 4) * 8;

  for (int kt = 0; kt < 1024; kt += 32) {
    gl_lds16(gA0 + kt, lA0);
    gl_lds16(gA1 + kt, lA1);
    gl_lds16(gB0 + kt, lB0);
    gl_lds16(gB1 + kt, lB1);
    __syncthreads();
    short8 af[4], bfr[4];
#pragma unroll
    for (int m = 0; m < 4; m++) {
      af[m]  = *(const short8*)&As[(wr * 64 + m * 16 + fro) * 32 + ko];
      bfr[m] = *(const short8*)&Bs[(wc * 64 + m * 16 + fro) * 32 + ko];
    }
#pragma unroll
    for (int m = 0; m < 4; m++)
#pragma unroll
      for (int n = 0; n < 4; n++)
        acc[m][n] = __builtin_amdgcn_mfma_f32_16x16x32_bf16(af[m], bfr[n], acc[m][n], 0, 0, 0);
    __syncthreads();
  }
}

// Kii_reg: rbf(ip,ip), diag = 1+noise; fused Gershgorin row |sum| atomics
__global__ __launch_bounds__(256) void gemm_kii(const u16* __restrict__ ipb,
                                                u16* __restrict__ kii,
                                                const float* __restrict__ ni,
                                                const float* __restrict__ ll,
                                                const float* __restrict__ ln,
                                                float* __restrict__ rs) {
  __shared__ u16 As[4096], Bs[4096];
  f32x4 acc[4][4] = {};
  small_core(ipb + (size_t)blockIdx.y * 131072, ipb + (size_t)blockIdx.x * 131072,
             As, Bs, acc);
  const int lane = threadIdx.x & 63;
  const int wave = threadIdx.x >> 6;
  const int wr = wave >> 1, wc = wave & 1;
  float inv2 = 0.5f * expf(-2.0f * ll[0]);
  float noise = expf(ln[0]);
#pragma unroll
  for (int m = 0; m < 4; m++)
#pragma unroll
    for (int j = 0; j < 4; j++) {
      const size_t grow = blockIdx.y * 128 + wr * 64 + m * 16 + (lane >> 4) * 4 + j;
      float rn = ni[grow];
      float part = 0.f;
#pragma unroll
      for (int n = 0; n < 4; n++) {
        const size_t gcol = blockIdx.x * 128 + wc * 64 + n * 16 + (lane & 15);
        float d2 = fmaxf(rn + ni[gcol] - 2.0f * acc[m][n][j], 0.0f);
        float kv = (grow == gcol) ? (1.0f + noise) : expf(-inv2 * d2);
        kii[grow * 1024 + gcol] = f2bf(kv);
        part += fabsf(kv);
      }
      part += __shfl_xor(part, 1);
      part += __shfl_xor(part, 2);
      part += __shfl_xor(part, 4);
      part += __shfl_xor(part, 8);
      if ((lane & 15) == 0) atomicAdd(&rs[grow], part);
    }
}

// batch1: z=0: R2 = I - 2cK + c^2*(K@K) ; z=1: T1 = 2W - c*(W@K)
__global__ __launch_bounds__(256) void gemm_batch1(const u16* __restrict__ kii,
                                                   const u16* __restrict__ Wb,
                                                   u16* __restrict__ R2b,
                                                   u16* __restrict__ T1b,
                                                   const float* __restrict__ sc) {
  __shared__ u16 As[4096], Bs[4096];
  f32x4 acc[4][4] = {};
  const int z = blockIdx.z;
  const u16* Abase = z ? Wb : kii;
  small_core(Abase + (size_t)blockIdx.y * 131072, kii + (size_t)blockIdx.x * 131072,
             As, Bs, acc);
  const int lane = threadIdx.x & 63;
  const int wave = threadIdx.x >> 6;
  const int wr = wave >> 1, wc = wave & 1;
  const float c = sc[0];
#pragma unroll
  for (int m = 0; m < 4; m++)
#pragma unroll
    for (int j = 0; j < 4; j++) {
      const size_t grow = blockIdx.y * 128 + wr * 64 + m * 16 + (lane >> 4) * 4 + j;
#pragma unroll
      for (int n = 0; n < 4; n++) {
        const size_t gcol = blockIdx.x * 128 + wc * 64 + n * 16 + (lane & 15);
        const size_t o = grow * 1024 + gcol;
        float v = acc[m][n][j];
        if (z == 0) {
          float idv = (grow == gcol) ? 1.0f : 0.0f;
          R2b[o] = f2bf(idv - 2.0f * c * bf2f(kii[o]) + c * c * v);
        } else {
          T1b[o] = f2bf(2.0f * bf2f(Wb[o]) - c * v);
        }
      }
    }
}

// batch2: z=0: U[0:1024]    = S = s*(1.5I - c/2*K + 11/16*R2 - 5c/16*(K@R2))
//         z=1: U[1024:2048] = W2T = c*(T1 + T1@R2)
__global__ __launch_bounds__(256) void gemm_batch2(const u16* __restrict__ kii,
                                                   const u16* __restrict__ R2b,
                                                   const u16* __restrict__ T1b,
                                                   u16* __restrict__ U,
                                                   const float* __restrict__ sc) {
  __shared__ u16 As[4096], Bs[4096];
  f32x4 acc[4][4] = {};
  const int z = blockIdx.z;
  const u16* Abase = z ? T1b : kii;
  small_core(Abase + (size_t)blockIdx.y * 131072, R2b + (size_t)blockIdx.x * 131072,
             As, Bs, acc);
  const int lane = threadIdx.x & 63;
  const int wave = threadIdx.x >> 6;
  const int wr = wave >> 1, wc = wave & 1;
  const float c = sc[0], s = sc[1];
#pragma unroll
  for (int m = 0; m < 4; m++)
#pragma unroll
    for (int j = 0; j < 4; j++) {
      const size_t grow = blockIdx.y * 128 + wr * 64 + m * 16 + (lane >> 4) * 4 + j;
#pragma unroll
      for (int n = 0; n < 4; n++) {
        const size_t gcol = blockIdx.x * 128 + wc * 64 + n * 16 + (lane & 15);
        const size_t o = grow * 1024 + gcol;
        float v = acc[m][n][j];
        if (z == 0) {
          float idv = (grow == gcol) ? 1.0f : 0.0f;
          U[o] = f2bf(s * (1.5f * idv - 0.5f * c * bf2f(kii[o]) +
                           0.6875f * bf2f(R2b[o]) - 0.3125f * c * v));
        } else {
          U[o + 1048576] = f2bf(c * (bf2f(T1b[o]) + v));
        }
      }
    }
}

// ---------- prep: f32 rows (R x 1024) -> bf16 + row sum-of-squares ----------
__global__ __launch_bounds__(256) void prep_rows(const float* __restrict__ in,
                                                 u16* __restrict__ outb,
                                                 float* __restrict__ norms, int R) {
  __shared__ float wsum[4];
  for (int r = blockIdx.x; r < R; r += gridDim.x) {
    const float4 v = ((const float4*)(in + (size_t)r * 1024))[threadIdx.x];
    float ss = v.x * v.x + v.y * v.y + v.z * v.z + v.w * v.w;
    us4 o; o.x = f2bf(v.x); o.y = f2bf(v.y); o.z = f2bf(v.z); o.w = f2bf(v.w);
    ((us4*)(outb + (size_t)r * 1024))[threadIdx.x] = o;
#pragma unroll
    for (int s = 32; s > 0; s >>= 1) ss += __shfl_xor(ss, s);
    if ((threadIdx.x & 63) == 0) wsum[threadIdx.x >> 6] = ss;
    __syncthreads();
    if (threadIdx.x == 0) norms[r] = wsum[0] + wsum[1] + wsum[2] + wsum[3];
    __syncthreads();
  }
}

// ---------- ip rows (norms) + W convert + rs zero, one kernel ----------
__global__ __launch_bounds__(256) void prep_ipw(const float* __restrict__ ip,
                                                const float* __restrict__ W,
                                                u16* __restrict__ ipb,
                                                u16* __restrict__ wbf,
                                                float* __restrict__ ni,
                                                float* __restrict__ rs) {
  __shared__ float wsum[4];
  int b = blockIdx.x;
  if (b < 1024) {
    const float4 v = ((const float4*)(ip + (size_t)b * 1024))[threadIdx.x];
    float ss = v.x * v.x + v.y * v.y + v.z * v.z + v.w * v.w;
    us4 o; o.x = f2bf(v.x); o.y = f2bf(v.y); o.z = f2bf(v.z); o.w = f2bf(v.w);
    ((us4*)(ipb + (size_t)b * 1024))[threadIdx.x] = o;
#pragma unroll
    for (int s = 32; s > 0; s >>= 1) ss += __shfl_xor(ss, s);
    if ((threadIdx.x & 63) == 0) wsum[threadIdx.x >> 6] = ss;
    __syncthreads();
    if (threadIdx.x == 0) {
      ni[b] = wsum[0] + wsum[1] + wsum[2] + wsum[3];
      rs[b] = 0.0f;
    }
  } else {
    int r = b - 1024;
    const float4 v = ((const float4*)(W + (size_t)r * 1024))[threadIdx.x];
    us4 o; o.x = f2bf(v.x); o.y = f2bf(v.y); o.z = f2bf(v.z); o.w = f2bf(v.w);
    ((us4*)(wbf + (size_t)r * 1024))[threadIdx.x] = o;
  }
}

__global__ __launch_bounds__(256) void gmax_inv(const float* __restrict__ rs,
                                                float* __restrict__ sc) {
  __shared__ float wm[4];
  float m = 0.f;
  for (int i = threadIdx.x; i < 1024; i += 256) m = fmaxf(m, rs[i]);
#pragma unroll
  for (int o = 32; o > 0; o >>= 1) m = fmaxf(m, __shfl_xor(m, o));
  if ((threadIdx.x & 63) == 0) wm[threadIdx.x >> 6] = m;
  __syncthreads();
  if (threadIdx.x == 0) {
    float c = 1.0f / fmaxf(fmaxf(wm[0], wm[1]), fmaxf(wm[2], wm[3]));
    sc[0] = c;
    sc[1] = sqrtf(c);
  }
}

extern "C" void kernel_launch(void* const* d_in, const int* in_sizes, int n_in,
                              void* d_out, int out_size, void* d_ws, size_t ws_size,
                              hipStream_t stream) {
  const float* x  = (const float*)d_in[0];
  const float* ip = (const float*)d_in[1];
  const float* ll = (const float*)d_in[2];
  const float* ln = (const float*)d_in[3];
  const float* W  = (const float*)d_in[4];

  char* ws = (char*)d_ws;
  const size_t MB = 1ull << 20;
  u16* kxib = (u16*)(ws + 0 * MB);    // 32 MiB
  u16* xbf  = (u16*)(ws + 32 * MB);   // 32 MiB
  u16* ipb  = (u16*)(ws + 64 * MB);   // 2 MiB
  u16* wbf  = (u16*)(ws + 66 * MB);   // 2 MiB
  u16* kii  = (u16*)(ws + 68 * MB);   // 2 MiB
  u16* R2b  = (u16*)(ws + 70 * MB);   // 2 MiB
  u16* Ub   = (u16*)(ws + 74 * MB);   // 4 MiB  [S ; W2T]
  u16* t1b  = (u16*)(ws + 78 * MB);   // 2 MiB
  float* nx = (float*)(ws + 80 * MB);
  float* qb = (float*)(ws + 80 * MB + 128 * 1024);
  float* ni = (float*)(ws + 80 * MB + 256 * 1024);
  float* rs = (float*)(ws + 80 * MB + 512 * 1024);
  float* sc = (float*)(ws + 80 * MB + 768 * 1024);

  float* meanO = (float*)d_out;
  float* varO  = meanO + 16777216ull;

  prep_rows<<<2048, 256, 0, stream>>>(x, xbf, nx, 16384);
  prep_ipw<<<2048, 256, 0, stream>>>(ip, W, ipb, wbf, ni, rs);

  // Kii_reg + fused Gershgorin row-sums
  gemm_kii<<<dim3(8, 8), 256, 0, stream>>>(ipb, kii, ni, ll, ln, rs);
  gmax_inv<<<1, 256, 0, stream>>>(rs, sc);

  // batched: {R2 ; T1} then {S -> U[0:1024] ; W2T -> U[1024:2048]}
  gemm_batch1<<<dim3(8, 8, 2), 256, 0, stream>>>(kii, wbf, R2b, t1b, sc);
  gemm_batch2<<<dim3(8, 8, 2), 256, 0, stream>>>(kii, R2b, t1b, Ub, sc);

  // Kxi = exp(-inv2 * d2(x, ip)); qb zeroed here
  gemm128<0><<<1024, 256, 0, stream>>>(xbf, ipb, nullptr, nullptr, kxib,
                                       nx, ni, ll, qb);
  // q[s] = ||Kxi@S||^2 rowwise (atomic)
  gemm128<2><<<1024, 256, 0, stream>>>(kxib, Ub, nullptr, nullptr, nullptr,
                                       nullptr, nullptr, nullptr, qb);
  // mean = Kxi@W2T^T -> d_out, fused var = softplus(1-q) broadcast
  gemm128<1><<<1024, 256, 0, stream>>>(kxib, Ub + 1048576, meanO, varO, nullptr,
                                       nullptr, nullptr, nullptr, qb);
}

// Round 11
// 212.662 us; speedup vs baseline: 1.2940x; 1.1281x over previous
//
#include <hip/hip_runtime.h>
#include <hip/hip_bf16.h>
#include <math.h>

// SentenceGP: B=16,S=1024,D=1024,M=1024,O=1024
// out = [mean (16,1024,1024) f32][softplus(var) (16,1024,1024) f32]
//
// Pipeline (R11 = R10 + fat-kernel overlap of the small serial chain):
//  prep_ipw: ip->bf16 + norms | W->bf16 | rs=0
//  fat1: kii(64 blocks, first) || prep_x(2048)      [kii hidden]
//  gmax: c = 1/max_rowsum, s = sqrt(c)
//  fat2: batch1{R2,T1}(128, first) || Kxi(1024)     [batch1 hidden]
//  batch2a: S -> U[0:1024]                          [64 blocks, exposed]
//  fat3: batch2b{W2T}(64, first) || q(1024)         [W2T hidden]
//  mean = Kxi@W2T^T + fused var -> d_out
//
// Big-GEMM body: 128x128 tile, BK=64, 4 waves, 64 KiB LDS, 2 blocks/CU,
// XOR-swizzled LDS, counted vmcnt(4)/tile, one s_barrier/phase (R10).

typedef unsigned short u16;
typedef __attribute__((ext_vector_type(8))) short short8;
typedef __attribute__((ext_vector_type(4))) float f32x4;
typedef __attribute__((ext_vector_type(4))) unsigned short us4;

__device__ __forceinline__ float bf2f(u16 b) {
  union { unsigned u; float f; } x; x.u = ((unsigned)b) << 16; return x.f;
}
__device__ __forceinline__ u16 f2bf(float f) {
  union { float f; unsigned u; } x; x.f = f;
  unsigned r = x.u + 0x7fffu + ((x.u >> 16) & 1u);
  return (u16)(r >> 16);
}

__device__ __forceinline__ void gl_lds16(const void* g, void* l) {
  __builtin_amdgcn_global_load_lds(
      (const __attribute__((address_space(1))) void*)g,
      (__attribute__((address_space(3))) void*)l, 16, 0, 0);
}

// =================== big GEMM body: 128^2, 4 waves, 2 blocks/CU ============
// EPI 0: Kxi = bf16(exp(-inv2*max(rn+cn-2c,0))); zeroes qb.
// EPI 1: mean f32 store + fused var = softplus(1-q[row]).
// EPI 2: q[row] += sum_col acc^2 (atomic).
template <int EPI>
__device__ __forceinline__ void big_body(
    int bid, u16* lds,
    const u16* Ag, const u16* Bg,
    float* outF, float* varF, u16* outB,
    const float* rowN, const float* colN,
    const float* p_ll, float* qb) {
  constexpr int NT = 16;  // K / 64
  const int tid = threadIdx.x;
  const int lane = tid & 63;
  const int wave = tid >> 6;                  // 4 waves
  const int wr = wave >> 1, wc = wave & 1;    // 2 x 2
  const int fro = lane & 15, khi = lane >> 4;
  const int xcd = bid & 7, j7 = bid >> 3;
  const size_t brow = (size_t)(xcd * 16 + (j7 >> 3));  // row-panel -> one XCD
  const size_t bcol = (size_t)(j7 & 7);

  if (EPI == 0) {  // zero q accumulator for the later q pass
    if (tid < 16) qb[(size_t)bid * 16 + tid] = 0.0f;
  }

  f32x4 acc[4][4] = {};

  auto stageA = [&](int tt, int bb) {
#pragma unroll
    for (int c = 0; c < 4; ++c) {
      const int ci = tid + 256 * c;      // 1024 chunks of 8 u16
      const int row = ci >> 3;           // 0..127
      const int gk = (ci & 7) ^ (row & 7);
      gl_lds16(Ag + (size_t)(brow * 128 + row) * 1024 + tt * 64 + gk * 8,
               &lds[bb * 16384 + ci * 8]);
    }
  };
  auto stageB = [&](int tt, int bb) {
#pragma unroll
    for (int c = 0; c < 4; ++c) {
      const int ci = tid + 256 * c;
      const int row = ci >> 3;
      const int gk = (ci & 7) ^ (row & 7);
      gl_lds16(Bg + (size_t)(bcol * 128 + row) * 1024 + tt * 64 + gk * 8,
               &lds[bb * 16384 + 8192 + ci * 8]);
    }
  };

  // prologue: A(0)+B(0) -> buf0, B(1) -> buf1. vmcnt(4): tile0 landed.
  stageA(0, 0);
  stageB(0, 0);
  stageB(1, 1);
  asm volatile("s_waitcnt vmcnt(4)" ::: "memory");
  __builtin_amdgcn_s_barrier();

  for (int t = 0; t < NT; ++t) {
    const int cb = t & 1;
    const int ab = cb * 16384;
    const int bb = cb * 16384 + 8192;
    short8 bfrag[4][2];
#pragma unroll
    for (int p = 0; p < 4; ++p) {
      short8 afr[2];
      const int rr = wr * 64 + p * 16 + fro;
#pragma unroll
      for (int s = 0; s < 2; ++s) {
        const int kl = (s * 4 + khi) ^ (rr & 7);
        afr[s] = *(const short8*)&lds[ab + (rr * 8 + kl) * 8];
      }
      if (p == 0) {
#pragma unroll
        for (int n = 0; n < 4; ++n) {
          const int cc = wc * 64 + n * 16 + fro;
#pragma unroll
          for (int s = 0; s < 2; ++s) {
            const int kl = (s * 4 + khi) ^ (cc & 7);
            bfrag[n][s] = *(const short8*)&lds[bb + (cc * 8 + kl) * 8];
          }
        }
        if (t + 1 < NT) stageA(t + 1, cb ^ 1);   // A(t-1) done @ t-1 p3
      } else if (p == 1) {
        if (t + 2 < NT) stageB(t + 2, cb);        // B(t) done @ p0
      }
      __builtin_amdgcn_s_setprio(1);
#pragma unroll
      for (int n = 0; n < 4; ++n)
#pragma unroll
        for (int s = 0; s < 2; ++s)
          acc[p][n] = __builtin_amdgcn_mfma_f32_16x16x32_bf16(
              afr[s], bfrag[n][s], acc[p][n], 0, 0, 0);
      __builtin_amdgcn_s_setprio(0);
      if (p == 3) {
        if (t < NT - 2) asm volatile("s_waitcnt vmcnt(4)" ::: "memory");
        else            asm volatile("s_waitcnt vmcnt(0)" ::: "memory");
      }
      __builtin_amdgcn_s_barrier();
    }
  }

  // ---- epilogue ----
  float inv2 = 0.f;
  if (EPI == 0) inv2 = 0.5f * expf(-2.0f * p_ll[0]);
#pragma unroll
  for (int m = 0; m < 4; m++) {
#pragma unroll
    for (int j = 0; j < 4; j++) {
      const size_t grow = brow * 128 + wr * 64 + m * 16 + khi * 4 + j;
      float rn = 0.f, sp = 0.f;
      if (EPI == 0) rn = rowN[grow];
      if (EPI == 1) {
        float vq = 1.0f - qb[grow];  // K_xx diag == 1 exactly
        sp = fmaxf(vq, 0.f) + log1pf(expf(-fabsf(vq)));
      }
      float part = 0.f;
#pragma unroll
      for (int n = 0; n < 4; n++) {
        const size_t gcol = bcol * 128 + wc * 64 + n * 16 + fro;
        const size_t o = grow * 1024 + gcol;
        float v = acc[m][n][j];
        if (EPI == 0) {
          float d2 = fmaxf(rn + colN[gcol] - 2.0f * v, 0.0f);
          outB[o] = f2bf(expf(-inv2 * d2));
        } else if (EPI == 1) {
          outF[o] = v;
          varF[o] = sp;
        } else {
          part += v * v;
        }
      }
      if (EPI == 2) {
        part += __shfl_xor(part, 1);
        part += __shfl_xor(part, 2);
        part += __shfl_xor(part, 4);
        part += __shfl_xor(part, 8);
        if (fro == 0) atomicAdd(&qb[grow], part);
      }
    }
  }
}

// =================== small 128^2 GEMM core (K=1024, B^T layout) ===========
__device__ __forceinline__ void small_core(const u16* Ap, const u16* Bp,
                                           u16* As, u16* Bs,
                                           f32x4 (&acc)[4][4]) {
  const int tid = threadIdx.x;
  const int lane = tid & 63;
  const int wave = tid >> 6;
  const int wr = wave >> 1, wc = wave & 1;
  const int idx0 = tid, idx1 = tid + 256;
  const u16* gA0 = Ap + (size_t)(idx0 >> 2) * 1024 + (size_t)(idx0 & 3) * 8;
  const u16* gA1 = Ap + (size_t)(idx1 >> 2) * 1024 + (size_t)(idx1 & 3) * 8;
  const u16* gB0 = Bp + (size_t)(idx0 >> 2) * 1024 + (size_t)(idx0 & 3) * 8;
  const u16* gB1 = Bp + (size_t)(idx1 >> 2) * 1024 + (size_t)(idx1 & 3) * 8;
  u16* lA0 = &As[idx0 * 8]; u16* lA1 = &As[idx1 * 8];
  u16* lB0 = &Bs[idx0 * 8]; u16* lB1 = &Bs[idx1 * 8];
  const int fro = lane & 15;
  const int ko = (lane >> 4) * 8;

  for (int kt = 0; kt < 1024; kt += 32) {
    gl_lds16(gA0 + kt, lA0);
    gl_lds16(gA1 + kt, lA1);
    gl_lds16(gB0 + kt, lB0);
    gl_lds16(gB1 + kt, lB1);
    __syncthreads();
    short8 af[4], bfr[4];
#pragma unroll
    for (int m = 0; m < 4; m++) {
      af[m]  = *(const short8*)&As[(wr * 64 + m * 16 + fro) * 32 + ko];
      bfr[m] = *(const short8*)&Bs[(wc * 64 + m * 16 + fro) * 32 + ko];
    }
#pragma unroll
    for (int m = 0; m < 4; m++)
#pragma unroll
      for (int n = 0; n < 4; n++)
        acc[m][n] = __builtin_amdgcn_mfma_f32_16x16x32_bf16(af[m], bfr[n], acc[m][n], 0, 0, 0);
    __syncthreads();
  }
}

// ---------- kii body: rbf(ip,ip), diag=1+noise, fused Gershgorin ----------
__device__ __forceinline__ void kii_body(int bid, u16* lds,
                                         const u16* ipb, u16* kii,
                                         const float* ni, const float* ll,
                                         const float* ln, float* rs) {
  const int by = bid >> 3, bx = bid & 7;
  f32x4 acc[4][4] = {};
  small_core(ipb + (size_t)by * 131072, ipb + (size_t)bx * 131072,
             lds, lds + 4096, acc);
  const int lane = threadIdx.x & 63;
  const int wave = threadIdx.x >> 6;
  const int wr = wave >> 1, wc = wave & 1;
  float inv2 = 0.5f * expf(-2.0f * ll[0]);
  float noise = expf(ln[0]);
#pragma unroll
  for (int m = 0; m < 4; m++)
#pragma unroll
    for (int j = 0; j < 4; j++) {
      const size_t grow = by * 128 + wr * 64 + m * 16 + (lane >> 4) * 4 + j;
      float rn = ni[grow];
      float part = 0.f;
#pragma unroll
      for (int n = 0; n < 4; n++) {
        const size_t gcol = bx * 128 + wc * 64 + n * 16 + (lane & 15);
        float d2 = fmaxf(rn + ni[gcol] - 2.0f * acc[m][n][j], 0.0f);
        float kv = (grow == gcol) ? (1.0f + noise) : expf(-inv2 * d2);
        kii[grow * 1024 + gcol] = f2bf(kv);
        part += fabsf(kv);
      }
      part += __shfl_xor(part, 1);
      part += __shfl_xor(part, 2);
      part += __shfl_xor(part, 4);
      part += __shfl_xor(part, 8);
      if ((lane & 15) == 0) atomicAdd(&rs[grow], part);
    }
}

// ---------- batch1 body: z=0: R2 = I-2cK+c^2*K@K ; z=1: T1 = 2W - c*W@K ----
__device__ __forceinline__ void batch1_body(int bid, u16* lds,
                                            const u16* kii, const u16* Wb,
                                            u16* R2b, u16* T1b,
                                            const float* sc) {
  const int z = bid >> 6, r = bid & 63;
  const int by = r >> 3, bx = r & 7;
  f32x4 acc[4][4] = {};
  const u16* Abase = z ? Wb : kii;
  small_core(Abase + (size_t)by * 131072, kii + (size_t)bx * 131072,
             lds, lds + 4096, acc);
  const int lane = threadIdx.x & 63;
  const int wave = threadIdx.x >> 6;
  const int wr = wave >> 1, wc = wave & 1;
  const float c = sc[0];
#pragma unroll
  for (int m = 0; m < 4; m++)
#pragma unroll
    for (int j = 0; j < 4; j++) {
      const size_t grow = by * 128 + wr * 64 + m * 16 + (lane >> 4) * 4 + j;
#pragma unroll
      for (int n = 0; n < 4; n++) {
        const size_t gcol = bx * 128 + wc * 64 + n * 16 + (lane & 15);
        const size_t o = grow * 1024 + gcol;
        float v = acc[m][n][j];
        if (z == 0) {
          float idv = (grow == gcol) ? 1.0f : 0.0f;
          R2b[o] = f2bf(idv - 2.0f * c * bf2f(kii[o]) + c * c * v);
        } else {
          T1b[o] = f2bf(2.0f * bf2f(Wb[o]) - c * v);
        }
      }
    }
}

// ---------- batch2 body: z=0: S -> U[0:1024] ; z=1: W2T -> U[1024:2048] ----
__device__ __forceinline__ void batch2_body(int z, int by, int bx, u16* lds,
                                            const u16* kii, const u16* R2b,
                                            const u16* T1b, u16* U,
                                            const float* sc) {
  f32x4 acc[4][4] = {};
  const u16* Abase = z ? T1b : kii;
  small_core(Abase + (size_t)by * 131072, R2b + (size_t)bx * 131072,
             lds, lds + 4096, acc);
  const int lane = threadIdx.x & 63;
  const int wave = threadIdx.x >> 6;
  const int wr = wave >> 1, wc = wave & 1;
  const float c = sc[0], s = sc[1];
#pragma unroll
  for (int m = 0; m < 4; m++)
#pragma unroll
    for (int j = 0; j < 4; j++) {
      const size_t grow = by * 128 + wr * 64 + m * 16 + (lane >> 4) * 4 + j;
#pragma unroll
      for (int n = 0; n < 4; n++) {
        const size_t gcol = bx * 128 + wc * 64 + n * 16 + (lane & 15);
        const size_t o = grow * 1024 + gcol;
        float v = acc[m][n][j];
        if (z == 0) {
          float idv = (grow == gcol) ? 1.0f : 0.0f;
          U[o] = f2bf(s * (1.5f * idv - 0.5f * c * bf2f(kii[o]) +
                           0.6875f * bf2f(R2b[o]) - 0.3125f * c * v));
        } else {
          U[o + 1048576] = f2bf(c * (bf2f(T1b[o]) + v));
        }
      }
    }
}

// ---------- prep_x body: x rows -> bf16 + row norms (stride 2048) ----------
__device__ __forceinline__ void prepx_body(int bid, u16* lds,
                                           const float* x, u16* xbf,
                                           float* nx) {
  float* wsum = (float*)lds;
  for (int r = bid; r < 16384; r += 2048) {
    const float4 v = ((const float4*)(x + (size_t)r * 1024))[threadIdx.x];
    float ss = v.x * v.x + v.y * v.y + v.z * v.z + v.w * v.w;
    us4 o; o.x = f2bf(v.x); o.y = f2bf(v.y); o.z = f2bf(v.z); o.w = f2bf(v.w);
    ((us4*)(xbf + (size_t)r * 1024))[threadIdx.x] = o;
#pragma unroll
    for (int s = 32; s > 0; s >>= 1) ss += __shfl_xor(ss, s);
    if ((threadIdx.x & 63) == 0) wsum[threadIdx.x >> 6] = ss;
    __syncthreads();
    if (threadIdx.x == 0) nx[r] = wsum[0] + wsum[1] + wsum[2] + wsum[3];
    __syncthreads();
  }
}

// =================== fat kernels ===================
// fat1: kii(64, first) || prep_x(2048)
__global__ __launch_bounds__(256) void fat1(
    const float* __restrict__ x, u16* __restrict__ xbf, float* __restrict__ nx,
    const u16* __restrict__ ipb, u16* __restrict__ kii,
    const float* __restrict__ ni, const float* __restrict__ ll,
    const float* __restrict__ ln, float* __restrict__ rs) {
  __shared__ u16 lds[8192];  // 16 KiB
  const int bid = blockIdx.x;
  if (bid < 64) kii_body(bid, lds, ipb, kii, ni, ll, ln, rs);
  else          prepx_body(bid - 64, lds, x, xbf, nx);
}

// fat2: batch1(128, first) || Kxi(1024)
__global__ __launch_bounds__(256, 2) void fat2(
    const u16* __restrict__ xbf, const u16* __restrict__ ipb,
    u16* __restrict__ kxib,
    const float* __restrict__ nx, const float* __restrict__ ni,
    const float* __restrict__ ll, float* __restrict__ qb,
    const u16* __restrict__ kii, const u16* __restrict__ wbf,
    u16* __restrict__ R2b, u16* __restrict__ t1b,
    const float* __restrict__ sc) {
  __shared__ u16 lds[32768];  // 64 KiB
  const int bid = blockIdx.x;
  if (bid < 128) batch1_body(bid, lds, kii, wbf, R2b, t1b, sc);
  else big_body<0>(bid - 128, lds, xbf, ipb, nullptr, nullptr, kxib,
                   nx, ni, ll, qb);
}

// batch2a: S only (z=0)
__global__ __launch_bounds__(256) void kbatch2a(
    const u16* __restrict__ kii, const u16* __restrict__ R2b,
    const u16* __restrict__ t1b, u16* __restrict__ U,
    const float* __restrict__ sc) {
  __shared__ u16 lds[8192];
  batch2_body(0, blockIdx.y, blockIdx.x, lds, kii, R2b, t1b, U, sc);
}

// fat3: batch2b{W2T}(64, first) || q(1024)
__global__ __launch_bounds__(256, 2) void fat3(
    const u16* __restrict__ kxib, const u16* __restrict__ U,
    float* __restrict__ qb,
    const u16* __restrict__ kii, const u16* __restrict__ R2b,
    const u16* __restrict__ t1b, u16* __restrict__ Uw,
    const float* __restrict__ sc) {
  __shared__ u16 lds[32768];
  const int bid = blockIdx.x;
  if (bid < 64) batch2_body(1, bid >> 3, bid & 7, lds, kii, R2b, t1b, Uw, sc);
  else big_body<2>(bid - 64, lds, kxib, U, nullptr, nullptr, nullptr,
                   nullptr, nullptr, nullptr, qb);
}

// mean pass
__global__ __launch_bounds__(256, 2) void kmean(
    const u16* __restrict__ kxib, const u16* __restrict__ w2t,
    float* __restrict__ meanO, float* __restrict__ varO,
    float* __restrict__ qb) {
  __shared__ u16 lds[32768];
  big_body<1>(blockIdx.x, lds, kxib, w2t, meanO, varO, nullptr,
              nullptr, nullptr, nullptr, qb);
}

// ---------- ip rows (norms) + W convert + rs zero ----------
__global__ __launch_bounds__(256) void prep_ipw(const float* __restrict__ ip,
                                                const float* __restrict__ W,
                                                u16* __restrict__ ipb,
                                                u16* __restrict__ wbf,
                                                float* __restrict__ ni,
                                                float* __restrict__ rs) {
  __shared__ float wsum[4];
  int b = blockIdx.x;
  if (b < 1024) {
    const float4 v = ((const float4*)(ip + (size_t)b * 1024))[threadIdx.x];
    float ss = v.x * v.x + v.y * v.y + v.z * v.z + v.w * v.w;
    us4 o; o.x = f2bf(v.x); o.y = f2bf(v.y); o.z = f2bf(v.z); o.w = f2bf(v.w);
    ((us4*)(ipb + (size_t)b * 1024))[threadIdx.x] = o;
#pragma unroll
    for (int s = 32; s > 0; s >>= 1) ss += __shfl_xor(ss, s);
    if ((threadIdx.x & 63) == 0) wsum[threadIdx.x >> 6] = ss;
    __syncthreads();
    if (threadIdx.x == 0) {
      ni[b] = wsum[0] + wsum[1] + wsum[2] + wsum[3];
      rs[b] = 0.0f;
    }
  } else {
    int r = b - 1024;
    const float4 v = ((const float4*)(W + (size_t)r * 1024))[threadIdx.x];
    us4 o; o.x = f2bf(v.x); o.y = f2bf(v.y); o.z = f2bf(v.z); o.w = f2bf(v.w);
    ((us4*)(wbf + (size_t)r * 1024))[threadIdx.x] = o;
  }
}

__global__ __launch_bounds__(256) void gmax_inv(const float* __restrict__ rs,
                                                float* __restrict__ sc) {
  __shared__ float wm[4];
  float m = 0.f;
  for (int i = threadIdx.x; i < 1024; i += 256) m = fmaxf(m, rs[i]);
#pragma unroll
  for (int o = 32; o > 0; o >>= 1) m = fmaxf(m, __shfl_xor(m, o));
  if ((threadIdx.x & 63) == 0) wm[threadIdx.x >> 6] = m;
  __syncthreads();
  if (threadIdx.x == 0) {
    float c = 1.0f / fmaxf(fmaxf(wm[0], wm[1]), fmaxf(wm[2], wm[3]));
    sc[0] = c;
    sc[1] = sqrtf(c);
  }
}

extern "C" void kernel_launch(void* const* d_in, const int* in_sizes, int n_in,
                              void* d_out, int out_size, void* d_ws, size_t ws_size,
                              hipStream_t stream) {
  const float* x  = (const float*)d_in[0];
  const float* ip = (const float*)d_in[1];
  const float* ll = (const float*)d_in[2];
  const float* ln = (const float*)d_in[3];
  const float* W  = (const float*)d_in[4];

  char* ws = (char*)d_ws;
  const size_t MB = 1ull << 20;
  u16* kxib = (u16*)(ws + 0 * MB);    // 32 MiB
  u16* xbf  = (u16*)(ws + 32 * MB);   // 32 MiB
  u16* ipb  = (u16*)(ws + 64 * MB);   // 2 MiB
  u16* wbf  = (u16*)(ws + 66 * MB);   // 2 MiB
  u16* kii  = (u16*)(ws + 68 * MB);   // 2 MiB
  u16* R2b  = (u16*)(ws + 70 * MB);   // 2 MiB
  u16* Ub   = (u16*)(ws + 74 * MB);   // 4 MiB  [S ; W2T]
  u16* t1b  = (u16*)(ws + 78 * MB);   // 2 MiB
  float* nx = (float*)(ws + 80 * MB);
  float* qb = (float*)(ws + 80 * MB + 128 * 1024);
  float* ni = (float*)(ws + 80 * MB + 256 * 1024);
  float* rs = (float*)(ws + 80 * MB + 512 * 1024);
  float* sc = (float*)(ws + 80 * MB + 768 * 1024);

  float* meanO = (float*)d_out;
  float* varO  = meanO + 16777216ull;

  // ip/W prep (kii's inputs) first
  prep_ipw<<<2048, 256, 0, stream>>>(ip, W, ipb, wbf, ni, rs);

  // kii (64, first) || prep_x (2048)
  fat1<<<2112, 256, 0, stream>>>(x, xbf, nx, ipb, kii, ni, ll, ln, rs);

  gmax_inv<<<1, 256, 0, stream>>>(rs, sc);

  // batch1 (128, first) || Kxi (1024); qb zeroed by Kxi blocks
  fat2<<<1152, 256, 0, stream>>>(xbf, ipb, kxib, nx, ni, ll, qb,
                                 kii, wbf, R2b, t1b, sc);

  // S -> U[0:1024]
  kbatch2a<<<dim3(8, 8), 256, 0, stream>>>(kii, R2b, t1b, Ub, sc);

  // batch2b{W2T} (64, first) || q (1024)
  fat3<<<1088, 256, 0, stream>>>(kxib, Ub, qb, kii, R2b, t1b, Ub, sc);

  // mean + fused var -> d_out
  kmean<<<1024, 256, 0, stream>>>(kxib, Ub + 1048576, meanO, varO, qb);
}